// Round 5
// baseline (369.762 us; speedup 1.0000x reference)
//
#include <hip/hip_runtime.h>
#include <hip/hip_bf16.h>
#include <hip/hip_cooperative_groups.h>
#include <stdint.h>

namespace cg = cooperative_groups;

// B=4, C=64, N=16384, K=16, CO=64 (fp32 I/O, int32 idx)
// Single cooperative kernel, 512 blocks x 256 thr (needs only 2 blocks/CU residency).
// Each block owns a 128-wide n-strip (2 GEMM tiles) of one batch, XCD-pinned.
#define NDIM 16384
#define KNB 16
#define BNK_F 1048576.0f

union Pack4 { __hip_bfloat16 h[4]; uint2 u; };

__global__ __launch_bounds__(256, 4) void fused_kernel(
    const float* __restrict__ x,            // (B, 64, N)
    const int* __restrict__ ei,             // (B, N, 16)
    const float* __restrict__ W,            // (64, 128)
    const float* __restrict__ gamma,        // (64)
    const float* __restrict__ beta,         // (64)
    float* __restrict__ out,                // (B, 64, N)
    __hip_bfloat16* __restrict__ y1g,       // ws: (B, N, 64) bf16
    __hip_bfloat16* __restrict__ y2g,       // ws: (B, N, 64) bf16
    float* __restrict__ partials,           // ws: (512, 128)
    float* __restrict__ stats)              // ws: (128)
{
    __shared__ alignas(16) unsigned int lds_w[64 * 68]; // packed (w1+w2 | w2<<16) bf16; reused as out tile
    __shared__ alignas(16) float        lds_x[64 * 68]; // x staging tile
    __shared__ float                    lds_r[512];     // reduction scratch

    cg::grid_group grid = cg::this_grid();

    const int tid = threadIdx.x;
    const int g   = blockIdx.x;               // 0..511
    // XCD pinning: batch b on XCD pair {2b, 2b+1} (blk->XCD is round-robin %8; perf-only heuristic)
    const int xcd = g & 7;
    const int b   = xcd >> 1;
    const int tg  = (g >> 3) | ((xcd & 1) << 6);  // 0..127
    const int n0  = tg << 7;                      // 128-wide strip

    // ---------------- phase 0: GEMM (2 tiles of 64) ----------------
    for (int i = tid; i < 4096; i += 256) {
        int c = i & 63, o = i >> 6;
        float w1 = W[o * 128 + c];
        float w2 = W[o * 128 + 64 + c];
        unsigned int u12 = (unsigned int)__bfloat16_as_ushort(__float2bfloat16(w1 + w2));
        unsigned int u2  = (unsigned int)__bfloat16_as_ushort(__float2bfloat16(w2));
        lds_w[c * 68 + o] = u12 | (u2 << 16);
    }

    const int o0  = (tid & 15) * 4;
    const int nl0 = (tid >> 4) * 4;

    for (int t = 0; t < 2; ++t) {
        const int nt = n0 + (t << 6);
        const float* xb = x + (size_t)b * 64 * NDIM + nt;
        __syncthreads();                      // protect lds_x reuse (t=1) / no-op cost at t=0
        for (int i = tid; i < 4096; i += 256) {
            int nl = i & 63, c = i >> 6;
            lds_x[c * 68 + nl] = xb[(size_t)c * NDIM + nl];
        }
        __syncthreads();                      // also covers lds_w staging at t=0

        float acc1[4][4] = {}, acc2[4][4] = {};
        #pragma unroll 4
        for (int c = 0; c < 64; ++c) {
            float4 xv = *(const float4*)&lds_x[c * 68 + nl0];
            uint4  wv = *(const uint4*)&lds_w[c * 68 + o0];
            const float xa[4] = { xv.x, xv.y, xv.z, xv.w };
            const unsigned int wu[4] = { wv.x, wv.y, wv.z, wv.w };
            #pragma unroll
            for (int j = 0; j < 4; ++j) {
                float w12 = __uint_as_float(wu[j] << 16);
                float w2f = __uint_as_float(wu[j] & 0xffff0000u);
                #pragma unroll
                for (int i = 0; i < 4; ++i) {
                    acc1[i][j] = fmaf(w12, xa[i], acc1[i][j]);
                    acc2[i][j] = fmaf(w2f, xa[i], acc2[i][j]);
                }
            }
        }
        const size_t bn0 = (size_t)b * NDIM + nt;
        #pragma unroll
        for (int i = 0; i < 4; ++i) {
            Pack4 p1, p2;
            #pragma unroll
            for (int j = 0; j < 4; ++j) {
                p1.h[j] = __float2bfloat16(acc1[i][j]);
                p2.h[j] = __float2bfloat16(acc2[i][j]);
            }
            size_t off = (bn0 + nl0 + i) * 64 + o0;
            *(uint2*)(y1g + off) = p1.u;
            *(uint2*)(y2g + off) = p2.u;
        }
    }
    grid.sync();

    // ---------------- phase 1: gather + max/min + partial stats ----------------
    const int w    = __builtin_amdgcn_readfirstlane(tid >> 6);  // force wave-uniform
    const int lane = tid & 63;
    const float gm = gamma[lane];
    const bool useMax = (gm >= 0.0f);
    const __hip_bfloat16* y2b = y2g + ((size_t)b * NDIM) * 64;

    float hsel[32];
    float ssum = 0.f, ssq = 0.f;
    #pragma unroll
    for (int t = 0; t < 2; ++t) {
        const int rowbase = b * NDIM + n0 + (t << 6) + w * 16;
        #pragma unroll 2
        for (int i = 0; i < 16; ++i) {
            const int row = rowbase + i;
            const float y1v = __bfloat162float(y1g[(size_t)row * 64 + lane]);
            const int* r = ei + (size_t)row * KNB;
            float hmax = -3.402823e38f, hmin = 3.402823e38f;
            #pragma unroll
            for (int k = 0; k < KNB; ++k) {
                int j = r[k];
                float h = y1v - __bfloat162float(y2b[(size_t)j * 64 + lane]);
                ssum += h;
                ssq  = fmaf(h, h, ssq);
                hmax = fmaxf(hmax, h);
                hmin = fminf(hmin, h);
            }
            hsel[t * 16 + i] = useMax ? hmax : hmin;
        }
    }
    __syncthreads();                  // lds_r free
    lds_r[w * 64 + lane]       = ssum;
    lds_r[256 + w * 64 + lane] = ssq;
    __syncthreads();
    if (tid < 128) {
        int c   = tid & 63;
        int off = (tid < 64) ? 0 : 256;
        float v = lds_r[off + c] + lds_r[off + 64 + c] + lds_r[off + 128 + c] + lds_r[off + 192 + c];
        partials[(size_t)g * 128 + tid] = v;
    }
    grid.sync();

    // ---------------- phase 2: block 0 reduces partials -> stats ----------------
    if (g == 0) {
        float acc = 0.f;
        const int c = tid & 127;
        for (int rr = tid >> 7; rr < 512; rr += 2)
            acc += partials[(size_t)rr * 128 + c];
        __syncthreads();
        lds_r[tid] = acc;
        __syncthreads();
        if (tid < 128) stats[tid] = lds_r[tid] + lds_r[tid + 128];
    }
    grid.sync();

    // ---------------- phase 3: BN + leaky + transpose + store ----------------
    const float mean  = stats[lane] * (1.0f / BNK_F);
    const float var   = stats[64 + lane] * (1.0f / BNK_F) - mean * mean;
    const float scale = gm * rsqrtf(var + 1e-5f);
    const float bias  = beta[lane] - mean * scale;

    float* tileo = (float*)lds_w;     // 64 x 65 floats (16640 B <= 17408 B)
    #pragma unroll
    for (int t = 0; t < 2; ++t) {
        const int nt = n0 + (t << 6);
        __syncthreads();              // protect tileo reuse across t
        #pragma unroll
        for (int i = 0; i < 16; ++i) {
            float v = fmaf(scale, hsel[t * 16 + i], bias);
            v = (v >= 0.f) ? v : 0.2f * v;
            tileo[(w * 16 + i) * 65 + lane] = v;
        }
        __syncthreads();
        for (int o = w; o < 64; o += 4)
            out[((size_t)(b * 64 + o) << 14) + nt + lane] = tileo[lane * 65 + o];
    }
}

extern "C" void kernel_launch(void* const* d_in, const int* in_sizes, int n_in,
                              void* d_out, int out_size, void* d_ws, size_t ws_size,
                              hipStream_t stream) {
    const float* x     = (const float*)d_in[0];
    const int*   ei    = (const int*)d_in[1];
    const float* W     = (const float*)d_in[2];
    const float* gamma = (const float*)d_in[3];
    const float* beta  = (const float*)d_in[4];
    float* out = (float*)d_out;

    char* ws = (char*)d_ws;
    __hip_bfloat16* y1g      = (__hip_bfloat16*)(ws);                     // 8 MiB
    __hip_bfloat16* y2g      = (__hip_bfloat16*)(ws + 8388608);           // 8 MiB
    float*          partials = (float*)(ws + 16777216);                   // 256 KiB
    float*          stats    = (float*)(ws + 16777216 + 262144);          // 512 B

    void* kargs[] = { (void*)&x, (void*)&ei, (void*)&W, (void*)&gamma, (void*)&beta,
                      (void*)&out, (void*)&y1g, (void*)&y2g, (void*)&partials, (void*)&stats };
    hipLaunchCooperativeKernel((const void*)fused_kernel, dim3(512), dim3(256),
                               kargs, 0, stream);
}

// Round 6
// 130.574 us; speedup vs baseline: 2.8318x; 2.8318x over previous
//
#include <hip/hip_runtime.h>
#include <hip/hip_bf16.h>
#include <stdint.h>

// B=4, C=64, N=16384, K=16, CO=64 (fp32 I/O, int32 idx)
// 3-dispatch pipeline:
//  k1 gemm:   y1=(W1+W2)x, y2=W2x -> bf16 (B,N,64); also zeroes stats
//  k2 gather: per row: min/max_k y2[idx], sum/sumsq via identities; XCD-pinned batches
//  k3 out:    finalize BN inline + affine + leaky + transpose (B,N,64)->(B,64,N)
#define NDIM 16384
#define KNB 16
#define BNK_F 1048576.0f

union Pack4 { __hip_bfloat16 h[4]; uint2 u; };

// ---------------- Kernel 1: y1/y2 GEMM (proven in round 2) ----------------
__global__ __launch_bounds__(256) void gemm_y_kernel(
    const float* __restrict__ x,            // (B, 64, N)
    const float* __restrict__ W,            // (64, 128)
    __hip_bfloat16* __restrict__ y1,        // (B, N, 64) bf16
    __hip_bfloat16* __restrict__ y2,        // (B, N, 64) bf16
    float* __restrict__ stats)              // zeroed here (harness poisons ws)
{
    __shared__ alignas(16) float Ws12[64 * 68];
    __shared__ alignas(16) float Ws2 [64 * 68];
    __shared__ alignas(16) float xs  [64 * 68];

    const int tid = threadIdx.x;
    if (blockIdx.x == 0 && tid < 128) stats[tid] = 0.0f;

    const int b  = blockIdx.x >> 8;
    const int n0 = (blockIdx.x & 255) << 6;

    for (int i = tid; i < 4096; i += 256) {
        int o = i >> 6, c = i & 63;
        float w1 = W[o * 128 + c];
        float w2 = W[o * 128 + 64 + c];
        Ws12[c * 68 + o] = w1 + w2;
        Ws2 [c * 68 + o] = w2;
    }
    const float* xb = x + (size_t)b * 64 * NDIM + n0;
    for (int i = tid; i < 4096; i += 256) {
        int c = i >> 6, nl = i & 63;
        xs[c * 68 + nl] = xb[(size_t)c * NDIM + nl];
    }
    __syncthreads();

    const int o0  = (tid & 15) * 4;
    const int nl0 = (tid >> 4) * 4;
    float acc1[4][4] = {};
    float acc2[4][4] = {};

    #pragma unroll 4
    for (int c = 0; c < 64; ++c) {
        const float4 w12 = *(const float4*)&Ws12[c * 68 + o0];
        const float4 w2v = *(const float4*)&Ws2 [c * 68 + o0];
        const float4 xv  = *(const float4*)&xs  [c * 68 + nl0];
        const float xa[4] = { xv.x,  xv.y,  xv.z,  xv.w  };
        const float wa[4] = { w12.x, w12.y, w12.z, w12.w };
        const float wb[4] = { w2v.x, w2v.y, w2v.z, w2v.w };
        #pragma unroll
        for (int i = 0; i < 4; ++i) {
            #pragma unroll
            for (int j = 0; j < 4; ++j) {
                acc1[i][j] = fmaf(wa[j], xa[i], acc1[i][j]);
                acc2[i][j] = fmaf(wb[j], xa[i], acc2[i][j]);
            }
        }
    }

    const size_t bn0 = (size_t)b * NDIM + n0;
    #pragma unroll
    for (int i = 0; i < 4; ++i) {
        Pack4 p1, p2;
        #pragma unroll
        for (int j = 0; j < 4; ++j) {
            p1.h[j] = __float2bfloat16(acc1[i][j]);
            p2.h[j] = __float2bfloat16(acc2[i][j]);
        }
        size_t off = (bn0 + nl0 + i) * 64 + o0;
        *(uint2*)(y1 + off) = p1.u;
        *(uint2*)(y2 + off) = p2.u;
    }
}

// ---------------- Kernel 2: gather + extremes + BN stats ----------------
// 1024 blocks x 256. XCD-pinned: xcd=g&7 -> batch b=xcd>>1, so each XCD's L2
// holds exactly its batch's 2 MB bf16 y2 during the gather.
__global__ __launch_bounds__(256, 4) void gather_kernel(
    const __hip_bfloat16* __restrict__ y1g,  // (B, N, 64)
    const __hip_bfloat16* __restrict__ y2g,  // (B, N, 64)
    const int* __restrict__ ei,              // (B, N, 16)
    const float* __restrict__ gamma,         // (64)
    float* __restrict__ hsel,                // (B, N, 64) fp32
    float* __restrict__ stats)               // [0..63]=sum, [64..127]=sumsq
{
    const int tid  = threadIdx.x;
    const int lane = tid & 63;
    const int w    = __builtin_amdgcn_readfirstlane(tid >> 6);  // wave-uniform
    const int g    = blockIdx.x;             // 0..1023
    const int xcd  = g & 7;
    const int b    = xcd >> 1;
    const int half = xcd & 1;
    const int lb   = g >> 3;                 // 0..127
    // 16 consecutive rows per wave
    const int row0 = b * NDIM + half * 8192 + lb * 64 + w * 16;

    const unsigned sgn = (gamma[lane] >= 0.0f) ? 0x80000000u : 0u;
    const unsigned short* y2u = (const unsigned short*)y2g + ((size_t)b * NDIM) * 64 + lane;

    float ssum = 0.f, ssq = 0.f;

    for (int rp = 0; rp < 16; rp += 2) {
        const int rowA = row0 + rp;
        const int rowB = rowA + 1;
        const int* ia = ei + (size_t)rowA * KNB;   // wave-uniform -> s_load
        const int* ib = ei + (size_t)rowB * KNB;

        unsigned ua[KNB], ub[KNB];
        #pragma unroll
        for (int k = 0; k < KNB; ++k) ua[k] = y2u[(size_t)ia[k] * 64];
        #pragma unroll
        for (int k = 0; k < KNB; ++k) ub[k] = y2u[(size_t)ib[k] * 64];

        const float y1a = __bfloat162float(y1g[(size_t)rowA * 64 + lane]);
        const float y1b = __bfloat162float(y1g[(size_t)rowB * 64 + lane]);

        float s2a = 0.f, q2a = 0.f, Ma = -3.402823e38f;
        float s2b = 0.f, q2b = 0.f, Mb = -3.402823e38f;
        #pragma unroll
        for (int k = 0; k < KNB; ++k) {
            unsigned ra = ua[k] << 16;
            unsigned rb = ub[k] << 16;
            float va = __uint_as_float(ra);
            float vb = __uint_as_float(rb);
            s2a += va;                 s2b += vb;
            q2a = fmaf(va, va, q2a);   q2b = fmaf(vb, vb, q2b);
            Ma = fmaxf(Ma, __uint_as_float(ra ^ sgn));
            Mb = fmaxf(Mb, __uint_as_float(rb ^ sgn));
        }
        // extreme y2 (min if sgn set, max otherwise)
        float ea = __uint_as_float(__float_as_uint(Ma) ^ sgn);
        float eb = __uint_as_float(__float_as_uint(Mb) ^ sgn);
        hsel[(size_t)rowA * 64 + lane] = y1a - ea;
        hsel[(size_t)rowB * 64 + lane] = y1b - eb;
        // sum_k (y1 - v_k) = 16*y1 - s2 ; sum_k (y1-v_k)^2 = (16y1 - 2 s2)*y1 + q2
        ssum += 16.f * y1a - s2a;
        ssum += 16.f * y1b - s2b;
        ssq  += fmaf(fmaf(-2.f, s2a, 16.f * y1a), y1a, q2a);
        ssq  += fmaf(fmaf(-2.f, s2b, 16.f * y1b), y1b, q2b);
    }

    __shared__ float rs[4][64];
    __shared__ float rq[4][64];
    rs[w][lane] = ssum;
    rq[w][lane] = ssq;
    __syncthreads();
    if (tid < 128) {
        int c = tid & 63;
        if (tid < 64) {
            float s = rs[0][c] + rs[1][c] + rs[2][c] + rs[3][c];
            atomicAdd(&stats[c], s);
        } else {
            float q = rq[0][c] + rq[1][c] + rq[2][c] + rq[3][c];
            atomicAdd(&stats[64 + c], q);
        }
    }
}

// ---------------- Kernel 3: finalize + affine + leaky + transpose ----------------
__global__ __launch_bounds__(256) void out_kernel(
    const float* __restrict__ hsel,          // (B, N, 64)
    const float* __restrict__ stats,
    const float* __restrict__ gamma,
    const float* __restrict__ beta,
    float* __restrict__ out)                 // (B, 64, N)
{
    __shared__ float tile[64 * 65];
    __shared__ float sc[64], bi[64];
    const int tid = threadIdx.x;
    if (tid < 64) {
        float mean = stats[tid] * (1.0f / BNK_F);
        float var  = stats[64 + tid] * (1.0f / BNK_F) - mean * mean;
        float s    = gamma[tid] * rsqrtf(var + 1e-5f);
        sc[tid] = s;
        bi[tid] = beta[tid] - mean * s;
    }
    __syncthreads();

    const int b  = blockIdx.x >> 8;
    const int n0 = (blockIdx.x & 255) << 6;
    const int lane = tid & 63;
    const size_t bn0 = (size_t)b * NDIM + n0;
    const float s  = sc[lane];
    const float bb = bi[lane];

    for (int nl = tid >> 6; nl < 64; nl += 4) {
        float v = fmaf(s, hsel[(bn0 + nl) * 64 + lane], bb);
        v = (v >= 0.0f) ? v : 0.2f * v;
        tile[nl * 65 + lane] = v;
    }
    __syncthreads();
    for (int o = tid >> 6; o < 64; o += 4)
        out[((size_t)(b * 64 + o) << 14) + n0 + lane] = tile[lane * 65 + o];
}

extern "C" void kernel_launch(void* const* d_in, const int* in_sizes, int n_in,
                              void* d_out, int out_size, void* d_ws, size_t ws_size,
                              hipStream_t stream) {
    const float* x     = (const float*)d_in[0];
    const int*   ei    = (const int*)d_in[1];
    const float* W     = (const float*)d_in[2];
    const float* gamma = (const float*)d_in[3];
    const float* beta  = (const float*)d_in[4];
    float* out = (float*)d_out;

    char* ws = (char*)d_ws;
    __hip_bfloat16* y1   = (__hip_bfloat16*)(ws);                 // 8 MiB
    __hip_bfloat16* y2   = (__hip_bfloat16*)(ws + 8388608);       // 8 MiB
    float*          hsel = (float*)(ws + 16777216);               // 16 MiB
    float*          stats= (float*)(ws + 33554432);               // 512 B

    gemm_y_kernel <<<dim3(1024), dim3(256), 0, stream>>>(x, W, y1, y2, stats);
    gather_kernel <<<dim3(1024), dim3(256), 0, stream>>>(y1, y2, ei, gamma, hsel, stats);
    out_kernel    <<<dim3(1024), dim3(256), 0, stream>>>(hsel, stats, gamma, beta, out);
}